// Round 4
// baseline (151.615 us; speedup 1.0000x reference)
//
#include <hip/hip_runtime.h>
#include <hip/hip_bf16.h>

#define NROWS 8192
#define DIM   256
#define BM    128                         // rows per block = 4 waves x 32
#define CS    16                          // column splits -> grid 64*16=1024 = 4/CU
#define COLS_PER_BLOCK (NROWS / CS)       // 512
#define NTILES (COLS_PER_BLOCK / 16)      // 32
#define NBUF   4
#define TILE_BYTES 8192                   // 16 cols x 512 B

typedef __attribute__((ext_vector_type(8))) short short8;
typedef __attribute__((ext_vector_type(4))) float f32x4;

__device__ __forceinline__ float bfbits2f(unsigned short u) {
    unsigned int x = ((unsigned int)u) << 16;
    float f; __builtin_memcpy(&f, &x, 4); return f;
}
__device__ __forceinline__ unsigned short f2bf(float x) {
    __hip_bfloat16 h = __float2bfloat16(x);
    unsigned short u; __builtin_memcpy(&u, &h, 2); return u;
}

// ---------------------------------------------------------------------------
// Kernel 1: L2-normalize rows fp32 -> bf16, plus global label histogram.
// ---------------------------------------------------------------------------
__global__ __launch_bounds__(256)
void normalize_kernel(const float* __restrict__ latent,
                      const int* __restrict__ labels,
                      unsigned short* __restrict__ zb,
                      int* __restrict__ hist) {
    const int wave = threadIdx.x >> 6, lane = threadIdx.x & 63;
    const int row = blockIdx.x * 4 + wave;
    const float4 v = ((const float4*)(latent + (size_t)row * DIM))[lane];
    float s = v.x * v.x + v.y * v.y + v.z * v.z + v.w * v.w;
    #pragma unroll
    for (int m = 32; m; m >>= 1) s += __shfl_xor(s, m, 64);
    const float sc = rsqrtf(s);
    ushort4 o;
    o.x = f2bf(v.x * sc); o.y = f2bf(v.y * sc);
    o.z = f2bf(v.z * sc); o.w = f2bf(v.w * sc);
    ((ushort4*)(zb + (size_t)row * DIM))[lane] = o;
    if (lane == 0) atomicAdd(&hist[labels[row]], 1);
}

// ---------------------------------------------------------------------------
// Kernel 2: per-label sums S[l] = sum of z rows with label l (fp32).
// 64 blocks: (row-group of 256 rows) x (dim half of 128). LDS 64 KB.
// Dim mapping d + 32c keeps ds atomics bank-conflict-free.
// ---------------------------------------------------------------------------
__global__ __launch_bounds__(1024)
void label_sum(const unsigned short* __restrict__ zb,
               const int* __restrict__ labels,
               float* __restrict__ S) {
    __shared__ float Sl[128 * 128];       // 64 KB
    const int tid = threadIdx.x;
    #pragma unroll
    for (int i = 0; i < 16; ++i) Sl[tid + i * 1024] = 0.f;
    __syncthreads();
    const int d = tid & 31;
    const int q = tid >> 5;               // 0..31 row-parallel groups
    const int rowBase = (blockIdx.x >> 1) * 256;
    const int half = (blockIdx.x & 1) * 128;
    for (int i = 0; i < 8; ++i) {
        const int r = rowBase + q * 8 + i;
        const int lab = labels[r];
        const unsigned short* zr = zb + (size_t)r * DIM + half;
        float* dst = &Sl[lab * 128 + d];
        #pragma unroll
        for (int c = 0; c < 4; ++c)
            atomicAdd(&dst[c * 32], bfbits2f(zr[d + c * 32]));
    }
    __syncthreads();
    #pragma unroll
    for (int i = 0; i < 16; ++i) {
        const int l = tid + i * 1024;
        atomicAdd(&S[(l >> 7) * DIM + half + (l & 127)], Sl[l]);
    }
}

// ---------------------------------------------------------------------------
// Kernel 3: fused exp-sum. 256 thr = 4 waves; wave owns 32 rows (A in regs).
// B tiles staged k-major: LDS chunk kk (1 KB) = 16 cols x 64 B of k-step kk,
// so compute ds_reads are contiguous (zero conflicts) with immediate offsets.
// 4-buffer ring, counted vmcnt(6), raw barriers.
// ---------------------------------------------------------------------------
__global__ __launch_bounds__(256, 4)
void ntxent_main(const unsigned short* __restrict__ zb,
                 float* __restrict__ se_sum) {
    __shared__ __align__(16) char ldsB[NBUF * TILE_BYTES];   // 32 KB

    const int tid  = threadIdx.x;
    const int wave = tid >> 6, lane = tid & 63;
    const int lrow = lane & 15, kgrp = lane >> 4;
    const int rb = blockIdx.x / CS, cb = blockIdx.x % CS;  // bid%8 ~ cb%8: XCD locality
    const int rowW = rb * BM + wave * 32;
    const int colStart = cb * COLS_PER_BLOCK;
    const int grow0 = rowW + kgrp * 4;

    // --- A fragments: 32 rows x K=256 in registers ---
    short8 a0[8], a1[8];
    {
        const short8* p0 = (const short8*)(zb + (size_t)(rowW + lrow) * DIM + kgrp * 8);
        const short8* p1 = (const short8*)(zb + (size_t)(rowW + 16 + lrow) * DIM + kgrp * 8);
        #pragma unroll
        for (int kk = 0; kk < 8; ++kk) { a0[kk] = p0[kk * 4]; a1[kk] = p1[kk * 4]; }
    }
    asm volatile("s_waitcnt vmcnt(0)" ::: "memory");   // exact vmcnt ledger from here

    // per-lane source offset: lane l supplies col (l>>2), bytes (l&3)*16 of a 64B k-chunk
    const char* zbytes = (const char*)zb;
    const int srcP = ((lane >> 2) * 512) + ((lane & 3) * 16);

    auto stage = [&](int tt) {
        const int buf = tt & (NBUF - 1);
        const size_t colByte = (size_t)(colStart + tt * 16) * 512;
        #pragma unroll
        for (int i = 0; i < 2; ++i) {
            const int ch = i * 4 + wave;               // chunk 0..7 (wave-uniform)
            const char* src = zbytes + colByte + ch * 64 + srcP;
            __builtin_amdgcn_global_load_lds(
                (const __attribute__((address_space(1))) void*)src,
                (__attribute__((address_space(3))) void*)(ldsB + buf * TILE_BYTES + ch * 1024),
                16, 0, 0);
        }
    };

    float se[8] = {0.f, 0.f, 0.f, 0.f, 0.f, 0.f, 0.f, 0.f};
    const int ldsoff = lrow * 64 + kgrp * 16;

    auto computeTile = [&](int t) {
        const int buf = t & (NBUF - 1);
        const char* base = ldsB + buf * TILE_BYTES + ldsoff;
        f32x4 c0 = {0.f, 0.f, 0.f, 0.f};
        f32x4 c1 = {0.f, 0.f, 0.f, 0.f};
        #pragma unroll
        for (int kk = 0; kk < 8; ++kk) {
            const short8 b = *(const short8*)(base + kk * 1024);
            c0 = __builtin_amdgcn_mfma_f32_16x16x32_bf16(a0[kk], b, c0, 0, 0, 0);
            c1 = __builtin_amdgcn_mfma_f32_16x16x32_bf16(a1[kk], b, c1, 0, 0, 0);
        }
        const int colBase = colStart + t * 16;
        const int gcol = colBase + lrow;
        const bool diagT = (colBase < rowW + 32) && (rowW < colBase + 16);
        #pragma unroll
        for (int j = 0; j < 4; ++j) {
            float e0 = exp2f(c0[j] * 14.4269504089f);   // exp(10*cos)
            float e1 = exp2f(c1[j] * 14.4269504089f);
            if (diagT) {                                 // wave-uniform branch
                if (gcol == grow0 + j)      e0 = 0.f;
                if (gcol == grow0 + 16 + j) e1 = 0.f;
            }
            se[j]     += e0;
            se[4 + j] += e1;
        }
    };

    // --- counted-vmcnt pipeline: 4-buffer ring, 3 tiles in flight ---
    stage(0); stage(1); stage(2); stage(3);

    #pragma unroll 1
    for (int t = 0; t < NTILES - 4; ++t) {
        asm volatile("s_waitcnt vmcnt(6)" ::: "memory");   // own 2 loads of tile t done
        __builtin_amdgcn_s_barrier();                      // everyone's loads landed
        asm volatile("" ::: "memory");
        computeTile(t);
        asm volatile("s_waitcnt lgkmcnt(0)" ::: "memory"); // ds_reads of buf retired
        __builtin_amdgcn_s_barrier();                      // safe to overwrite buf
        stage(t + 4);
    }
    asm volatile("s_waitcnt vmcnt(6)" ::: "memory");
    __builtin_amdgcn_s_barrier();
    asm volatile("" ::: "memory");
    computeTile(NTILES - 4);
    asm volatile("s_waitcnt vmcnt(4)" ::: "memory");
    __builtin_amdgcn_s_barrier();
    asm volatile("" ::: "memory");
    computeTile(NTILES - 3);
    asm volatile("s_waitcnt vmcnt(2)" ::: "memory");
    __builtin_amdgcn_s_barrier();
    asm volatile("" ::: "memory");
    computeTile(NTILES - 2);
    asm volatile("s_waitcnt vmcnt(0)" ::: "memory");
    __builtin_amdgcn_s_barrier();
    asm volatile("" ::: "memory");
    computeTile(NTILES - 1);

    // --- reduce over 16 col-lanes, one atomic set per wave ---
    #pragma unroll
    for (int j = 0; j < 8; ++j) {
        #pragma unroll
        for (int m = 1; m < 16; m <<= 1) se[j] += __shfl_xor(se[j], m, 64);
    }
    if (lrow == 0) {
        #pragma unroll
        for (int j = 0; j < 4; ++j) {
            atomicAdd(&se_sum[grow0 + j],      se[j]);
            atomicAdd(&se_sum[grow0 + 16 + j], se[4 + j]);
        }
    }
}

// ---------------------------------------------------------------------------
// Kernel 4: per-row loss. ps = z_r . S[lab_r]; self term z_r . z_r exact.
// 128 blocks x 4 waves, 16 rows per wave.
// ---------------------------------------------------------------------------
__global__ __launch_bounds__(256)
void ntxent_final(const unsigned short* __restrict__ zb,
                  const int* __restrict__ labels,
                  const float* __restrict__ se_sum,
                  const float* __restrict__ S,
                  const int* __restrict__ hist,
                  float* __restrict__ acc) {
    const int wave = threadIdx.x >> 6, lane = threadIdx.x & 63;
    const int wg = blockIdx.x * 4 + wave;     // 0..511
    float contrib = 0.f, hp = 0.f;
    for (int i = 0; i < 16; ++i) {
        const int r = wg * 16 + i;
        const int lab = labels[r];
        const ushort4 zv = ((const ushort4*)(zb + (size_t)r * DIM))[lane];
        const float4  sv = ((const float4*)(S + lab * DIM))[lane];
        const float z0 = bfbits2f(zv.x), z1 = bfbits2f(zv.y),
                    z2 = bfbits2f(zv.z), z3 = bfbits2f(zv.w);
        float dp = z0 * sv.x + z1 * sv.y + z2 * sv.z + z3 * sv.w;
        float sd = z0 * z0 + z1 * z1 + z2 * z2 + z3 * z3;
        #pragma unroll
        for (int m = 32; m; m >>= 1) {
            dp += __shfl_xor(dp, m, 64);
            sd += __shfl_xor(sd, m, 64);
        }
        if (lane == 0) {
            const int n = hist[lab] - 1;
            if (n > 0) {
                contrib += __logf(se_sum[r]) - 10.0f * (dp - sd) / (float)n;
                hp += 1.0f;
            }
        }
    }
    if (lane == 0) {
        atomicAdd(&acc[0], contrib);
        atomicAdd(&acc[1], hp);
    }
}

// ---------------------------------------------------------------------------
// Kernel 5: finalize scalar
// ---------------------------------------------------------------------------
__global__ void finalize_kernel(const float* __restrict__ acc,
                                float* __restrict__ out) {
    out[0] = acc[0] / fmaxf(acc[1], 1.0f);
}

extern "C" void kernel_launch(void* const* d_in, const int* in_sizes, int n_in,
                              void* d_out, int out_size, void* d_ws, size_t ws_size,
                              hipStream_t stream) {
    const float* latent = (const float*)d_in[0];
    const int*   labels = (const int*)d_in[1];
    float* out = (float*)d_out;

    unsigned short* zb = (unsigned short*)d_ws;
    char* p = (char*)d_ws + (size_t)NROWS * DIM * sizeof(unsigned short);
    float* se_sum = (float*)p;                      // 32768 B
    float* S      = (float*)(p + 32768);            // 131072 B
    int*   hist   = (int*)  (p + 32768 + 131072);   // 512 B
    float* acc    = (float*)(p + 32768 + 131072 + 512); // 8 B

    hipMemsetAsync(p, 0, 32768 + 131072 + 512 + 8, stream);
    normalize_kernel<<<NROWS / 4, 256, 0, stream>>>(latent, labels, zb, hist);
    ntxent_main<<<(NROWS / BM) * CS, 256, 0, stream>>>(zb, se_sum);
    label_sum<<<64, 1024, 0, stream>>>(zb, labels, S);
    ntxent_final<<<NROWS / 64, 256, 0, stream>>>(zb, labels, se_sum, S, hist, acc);
    finalize_kernel<<<1, 1, 0, stream>>>(acc, out);
}

// Round 5
// 149.152 us; speedup vs baseline: 1.0165x; 1.0165x over previous
//
#include <hip/hip_runtime.h>
#include <hip/hip_bf16.h>

#define NROWS 8192
#define DIM   256
#define BM    256                         // rows per block = 4 waves x 64
#define CS    16                          // column splits -> grid 32*16=512 = 2/CU
#define COLS_PER_BLOCK (NROWS / CS)       // 512
#define NTILES (COLS_PER_BLOCK / 16)      // 32
#define NBUF   4
#define TILE_BYTES 8192                   // 16 cols x 512 B
// zb stores z * SQ, SQ^2 = 10*log2(e) = 14.4269504089 -> MFMA gives 14.43*cos
#define SQ_SCALE 3.798282387f
#define LN2      0.69314718056f           // 10/14.4269504089

typedef __attribute__((ext_vector_type(8))) short short8;
typedef __attribute__((ext_vector_type(4))) float f32x4;

__device__ __forceinline__ float bfbits2f(unsigned short u) {
    unsigned int x = ((unsigned int)u) << 16;
    float f; __builtin_memcpy(&f, &x, 4); return f;
}
__device__ __forceinline__ unsigned short f2bf(float x) {
    __hip_bfloat16 h = __float2bfloat16(x);
    unsigned short u; __builtin_memcpy(&u, &h, 2); return u;
}

// ---------------------------------------------------------------------------
// Kernel 1: L2-normalize rows fp32 -> bf16 scaled by SQ_SCALE; label histogram.
// ---------------------------------------------------------------------------
__global__ __launch_bounds__(256)
void normalize_kernel(const float* __restrict__ latent,
                      const int* __restrict__ labels,
                      unsigned short* __restrict__ zb,
                      int* __restrict__ hist) {
    const int wave = threadIdx.x >> 6, lane = threadIdx.x & 63;
    const int row = blockIdx.x * 4 + wave;
    const float4 v = ((const float4*)(latent + (size_t)row * DIM))[lane];
    float s = v.x * v.x + v.y * v.y + v.z * v.z + v.w * v.w;
    #pragma unroll
    for (int m = 32; m; m >>= 1) s += __shfl_xor(s, m, 64);
    const float sc = rsqrtf(s) * SQ_SCALE;
    ushort4 o;
    o.x = f2bf(v.x * sc); o.y = f2bf(v.y * sc);
    o.z = f2bf(v.z * sc); o.w = f2bf(v.w * sc);
    ((ushort4*)(zb + (size_t)row * DIM))[lane] = o;
    if (lane == 0) atomicAdd(&hist[labels[row]], 1);
}

// ---------------------------------------------------------------------------
// Kernel 2: fused exp-sum. 256 thr = 4 waves; wave owns 64 rows (A = 128 VGPR).
// B tile (16 cols x K=256) staged k-major, LANE-MAJOR within each 1 KB chunk:
// slot for (col,kgrp) lives at byte lane*16 -> ds_read_b128 is the canonical
// contiguous stride-16 pattern (conflict-free), address = base + imm.
// 4-buffer ring, counted vmcnt(6), loop unrolled x4 so buf is compile-time.
// ---------------------------------------------------------------------------
__global__ __launch_bounds__(256, 2)
void ntxent_main(const unsigned short* __restrict__ zb,
                 float* __restrict__ se_sum) {
    __shared__ __align__(16) char ldsB[NBUF * TILE_BYTES];   // 32 KB

    const int tid  = threadIdx.x;
    const int wave = tid >> 6, lane = tid & 63;
    const int lrow = lane & 15, kgrp = lane >> 4;
    const int rb = blockIdx.x / CS, cb = blockIdx.x % CS;  // bid%8 ~ cb%8: XCD locality
    const int rowW = rb * BM + wave * 64;
    const int colStart = cb * COLS_PER_BLOCK;
    const int g0 = rowW + kgrp * 4;

    // --- A fragments: 64 rows x K=256 in registers (128 VGPR) ---
    short8 a[4][8];
    #pragma unroll
    for (int q = 0; q < 4; ++q) {
        const short8* p = (const short8*)(zb + (size_t)(rowW + q * 16 + lrow) * DIM + kgrp * 8);
        #pragma unroll
        for (int kk = 0; kk < 8; ++kk) a[q][kk] = p[kk * 4];
    }
    asm volatile("s_waitcnt vmcnt(0)" ::: "memory");   // exact vmcnt ledger from here

    // lane l stages col (l&15), k-bytes (l>>4)*16 of each 64 B k-chunk -> LDS byte l*16
    const char* zbytes = (const char*)zb;
    const char* srcBase = zbytes + (size_t)colStart * 512
                        + (lane & 15) * 512 + (lane >> 4) * 16;

    auto stage = [&](int t, int buf) {
        const char* s0 = srcBase + (size_t)t * 8192 + wave * 64;
        __builtin_amdgcn_global_load_lds(
            (const __attribute__((address_space(1))) void*)s0,
            (__attribute__((address_space(3))) void*)(ldsB + buf * 8192 + wave * 1024),
            16, 0, 0);
        __builtin_amdgcn_global_load_lds(
            (const __attribute__((address_space(1))) void*)(s0 + 256),
            (__attribute__((address_space(3))) void*)(ldsB + buf * 8192 + wave * 1024 + 4096),
            16, 0, 0);
    };

    float se[16];
    #pragma unroll
    for (int i = 0; i < 16; ++i) se[i] = 0.f;
    const char* ldsRd = ldsB + lane * 16;

    auto computeTile = [&](int t, int buf) {
        f32x4 c[4];
        #pragma unroll
        for (int q = 0; q < 4; ++q) c[q] = (f32x4){0.f, 0.f, 0.f, 0.f};
        #pragma unroll
        for (int kk = 0; kk < 8; ++kk) {
            const short8 b = *(const short8*)(ldsRd + buf * 8192 + kk * 1024);
            c[0] = __builtin_amdgcn_mfma_f32_16x16x32_bf16(a[0][kk], b, c[0], 0, 0, 0);
            c[1] = __builtin_amdgcn_mfma_f32_16x16x32_bf16(a[1][kk], b, c[1], 0, 0, 0);
            c[2] = __builtin_amdgcn_mfma_f32_16x16x32_bf16(a[2][kk], b, c[2], 0, 0, 0);
            c[3] = __builtin_amdgcn_mfma_f32_16x16x32_bf16(a[3][kk], b, c[3], 0, 0, 0);
        }
        const int colBase = colStart + t * 16;
        const int gcol = colBase + lrow;
        float e[16];
        #pragma unroll
        for (int q = 0; q < 4; ++q)
            #pragma unroll
            for (int j = 0; j < 4; ++j) e[q * 4 + j] = exp2f(c[q][j]);
        if ((colBase < rowW + 64) && (rowW < colBase + 16)) {   // wave-uniform diag tile
            #pragma unroll
            for (int q = 0; q < 4; ++q)
                #pragma unroll
                for (int j = 0; j < 4; ++j)
                    if (gcol == g0 + q * 16 + j) e[q * 4 + j] = 0.f;
        }
        #pragma unroll
        for (int i = 0; i < 16; ++i) se[i] += e[i];
    };

    // --- counted-vmcnt pipeline: 4-buffer ring, 3 tiles in flight ---
    stage(0, 0); stage(1, 1); stage(2, 2); stage(3, 3);

    #pragma unroll 1
    for (int t = 0; t < NTILES - 4; t += 4) {       // 28/4 = 7 iterations
        #pragma unroll
        for (int p = 0; p < 4; ++p) {               // buf = (t+p)&3 = p
            asm volatile("s_waitcnt vmcnt(6)" ::: "memory");
            __builtin_amdgcn_s_barrier();
            asm volatile("" ::: "memory");
            computeTile(t + p, p);
            asm volatile("s_waitcnt lgkmcnt(0)" ::: "memory");
            __builtin_amdgcn_s_barrier();
            stage(t + p + 4, p);
        }
    }
    asm volatile("s_waitcnt vmcnt(6)" ::: "memory");
    __builtin_amdgcn_s_barrier();
    asm volatile("" ::: "memory");
    computeTile(NTILES - 4, 0);
    asm volatile("s_waitcnt vmcnt(4)" ::: "memory");
    __builtin_amdgcn_s_barrier();
    asm volatile("" ::: "memory");
    computeTile(NTILES - 3, 1);
    asm volatile("s_waitcnt vmcnt(2)" ::: "memory");
    __builtin_amdgcn_s_barrier();
    asm volatile("" ::: "memory");
    computeTile(NTILES - 2, 2);
    asm volatile("s_waitcnt vmcnt(0)" ::: "memory");
    __builtin_amdgcn_s_barrier();
    asm volatile("" ::: "memory");
    computeTile(NTILES - 1, 3);

    // --- reduce over 16 col-lanes, one atomic set per kgrp leader ---
    #pragma unroll
    for (int i = 0; i < 16; ++i) {
        #pragma unroll
        for (int m = 1; m < 16; m <<= 1) se[i] += __shfl_xor(se[i], m, 64);
    }
    if (lrow == 0) {
        #pragma unroll
        for (int i = 0; i < 16; ++i)
            atomicAdd(&se_sum[g0 + (i >> 2) * 16 + (i & 3)], se[i]);
    }
}

// ---------------------------------------------------------------------------
// Kernel 3: per-label partial sums, atomic-free to global.
// 64 blocks = (32 row-groups of 256 rows) x (2 dim halves). LDS 64 KB,
// pipelined no-return ds_add_f32 (conflict-free: bank = d mod 32).
// ---------------------------------------------------------------------------
__global__ __launch_bounds__(256)
void label_partial(const unsigned short* __restrict__ zb,
                   const int* __restrict__ labels,
                   float* __restrict__ partialS) {
    __shared__ float Sl[128 * 128];       // 64 KB
    const int tid = threadIdx.x;
    #pragma unroll
    for (int i = 0; i < 64; ++i) Sl[tid + i * 256] = 0.f;
    __syncthreads();
    const int d = tid & 127, rpar = tid >> 7;
    const int rowBase = (blockIdx.x >> 1) * 256;
    const int half = (blockIdx.x & 1) * 128;
    #pragma unroll 1
    for (int r0 = 0; r0 < 256; r0 += 16) {
        float v[8]; int lab[8];
        #pragma unroll
        for (int i = 0; i < 8; ++i) {
            const int r = rowBase + r0 + i * 2 + rpar;
            v[i]   = bfbits2f(zb[(size_t)r * DIM + half + d]);
            lab[i] = labels[r];
        }
        #pragma unroll
        for (int i = 0; i < 8; ++i) atomicAdd(&Sl[lab[i] * 128 + d], v[i]);
    }
    __syncthreads();
    #pragma unroll
    for (int i = 0; i < 64; ++i)
        partialS[(size_t)blockIdx.x * 16384 + tid + i * 256] = Sl[tid + i * 256];
}

// ---------------------------------------------------------------------------
// Kernel 4: reduce 64 partials -> S[128][256] (scaled by SQ_SCALE).
// ---------------------------------------------------------------------------
__global__ __launch_bounds__(256)
void label_reduce(const float* __restrict__ partialS,
                  float* __restrict__ S) {
    const int i = blockIdx.x * 256 + threadIdx.x;   // 0..32767
    const int half = i >> 14, rest = i & 16383;     // rest = l*128 + d
    float s = 0.f;
    #pragma unroll
    for (int g = 0; g < 32; ++g) s += partialS[(size_t)(g * 2 + half) * 16384 + rest];
    S[(rest >> 7) * 256 + half * 128 + (rest & 127)] = s;
}

// ---------------------------------------------------------------------------
// Kernel 5: per-row loss. dp = zs_r.S[lab] (scaled 14.43x); sd = zs_r.zs_r
// excludes self exactly; true 10*(sum_pos cos)/n = LN2*(dp-sd)/n.
// ---------------------------------------------------------------------------
__global__ __launch_bounds__(256)
void ntxent_final(const unsigned short* __restrict__ zb,
                  const int* __restrict__ labels,
                  const float* __restrict__ se_sum,
                  const float* __restrict__ S,
                  const int* __restrict__ hist,
                  float* __restrict__ acc) {
    const int wave = threadIdx.x >> 6, lane = threadIdx.x & 63;
    const int wg = blockIdx.x * 4 + wave;     // 0..511
    float contrib = 0.f, hp = 0.f;
    for (int i = 0; i < 16; ++i) {
        const int r = wg * 16 + i;
        const int lab = labels[r];
        const ushort4 zv = ((const ushort4*)(zb + (size_t)r * DIM))[lane];
        const float4  sv = ((const float4*)(S + lab * DIM))[lane];
        const float z0 = bfbits2f(zv.x), z1 = bfbits2f(zv.y),
                    z2 = bfbits2f(zv.z), z3 = bfbits2f(zv.w);
        float dp = z0 * sv.x + z1 * sv.y + z2 * sv.z + z3 * sv.w;
        float sd = z0 * z0 + z1 * z1 + z2 * z2 + z3 * z3;
        #pragma unroll
        for (int m = 32; m; m >>= 1) {
            dp += __shfl_xor(dp, m, 64);
            sd += __shfl_xor(sd, m, 64);
        }
        if (lane == 0) {
            const int n = hist[lab] - 1;
            if (n > 0) {
                contrib += __logf(se_sum[r]) - LN2 * (dp - sd) / (float)n;
                hp += 1.0f;
            }
        }
    }
    if (lane == 0) {
        atomicAdd(&acc[0], contrib);
        atomicAdd(&acc[1], hp);
    }
}

__global__ void finalize_kernel(const float* __restrict__ acc,
                                float* __restrict__ out) {
    out[0] = acc[0] / fmaxf(acc[1], 1.0f);
}

extern "C" void kernel_launch(void* const* d_in, const int* in_sizes, int n_in,
                              void* d_out, int out_size, void* d_ws, size_t ws_size,
                              hipStream_t stream) {
    const float* latent = (const float*)d_in[0];
    const int*   labels = (const int*)d_in[1];
    float* out = (float*)d_out;

    unsigned short* zb = (unsigned short*)d_ws;                       // 4 MB
    char* p = (char*)d_ws + (size_t)NROWS * DIM * sizeof(unsigned short);
    float* partialS = (float*)p;                                      // 4 MB (64 x 16384)
    char* q = p + (size_t)64 * 16384 * sizeof(float);
    float* se_sum = (float*)q;                                        // 32768 B
    float* S      = (float*)(q + 32768);                              // 131072 B
    int*   hist   = (int*)  (q + 32768 + 131072);                     // 512 B
    float* acc    = (float*)(q + 32768 + 131072 + 512);               // 8 B

    hipMemsetAsync(q, 0, 32768 + 131072 + 512 + 8, stream);
    normalize_kernel<<<NROWS / 4, 256, 0, stream>>>(latent, labels, zb, hist);
    ntxent_main<<<(NROWS / BM) * CS, 256, 0, stream>>>(zb, se_sum);
    label_partial<<<64, 256, 0, stream>>>(zb, labels, partialS);
    label_reduce<<<128, 256, 0, stream>>>(partialS, S);
    ntxent_final<<<NROWS / 64, 256, 0, stream>>>(zb, labels, se_sum, S, hist, acc);
    finalize_kernel<<<1, 1, 0, stream>>>(acc, out);
}

// Round 6
// 68.633 us; speedup vs baseline: 2.2091x; 2.1732x over previous
//
#include <hip/hip_runtime.h>
#include <hip/hip_bf16.h>

#define NROWS 8192
#define DIM   256
#define WROWS 64                   // rows per wave (A fully in registers)
#define STRIPS 32                  // column strips
#define CPW   (NROWS / STRIPS)     // 256 cols per wave
#define NT    (CPW / 16)           // 16 tiles per wave
// zk stores z * SQ_SCALE, SQ_SCALE^2 = 10*log2(e) -> MFMA gives 14.43*cos,
// so exp(sim) = exp2(mfma_out) directly.
#define SQ_SCALE 3.798282387f
#define LN2      0.69314718056f    // 10 / 14.4269504089
#define SELFV    14.4269504089f    // scaled self-similarity

typedef __attribute__((ext_vector_type(8))) short short8;
typedef __attribute__((ext_vector_type(4))) float f32x4;

__device__ __forceinline__ unsigned short f2bf(float x) {
    __hip_bfloat16 h = __float2bfloat16(x);
    unsigned short u; __builtin_memcpy(&u, &h, 2); return u;
}

// ---------------------------------------------------------------------------
// Kernel 1: L2-normalize rows fp32 -> bf16*SQ_SCALE, scattered into the
// fragment-native K-major layout:
//   element (row,d) -> ushort index
//   (row>>4)*4096 + (d>>5)*512 + ((d>>3)&3)*128 + (row&15)*8 + (d&7)
// so an MFMA fragment (16 rows/cols x 32-k-chunk) is 64 lanes x contiguous 16B.
// ---------------------------------------------------------------------------
__global__ __launch_bounds__(256)
void normalize_kernel(const float* __restrict__ latent,
                      unsigned short* __restrict__ zk) {
    const int wave = threadIdx.x >> 6, lane = threadIdx.x & 63;
    const int row = blockIdx.x * 4 + wave;
    const float4 v = ((const float4*)(latent + (size_t)row * DIM))[lane];
    float s = v.x * v.x + v.y * v.y + v.z * v.z + v.w * v.w;
    #pragma unroll
    for (int m = 32; m; m >>= 1) s += __shfl_xor(s, m, 64);
    const float sc = rsqrtf(s) * SQ_SCALE;
    ushort4 o;
    o.x = f2bf(v.x * sc); o.y = f2bf(v.y * sc);
    o.z = f2bf(v.z * sc); o.w = f2bf(v.w * sc);
    const int d0 = lane * 4;
    const size_t idx = (size_t)(row >> 4) * 4096 + (d0 >> 5) * 512
                     + ((d0 >> 3) & 3) * 128 + (row & 15) * 8 + (d0 & 7);
    *(ushort4*)(zk + idx) = o;
}

// ---------------------------------------------------------------------------
// Kernel 2: fused sim reductions, registers only (no LDS staging, no barriers
// in the sweep). 256 thr = 4 waves; all 4 waves share the block's 64 rows
// (A = 128 VGPR) but sweep different 256-col strips. B tile = 8 contiguous
// 1KB loads, single-buffered, prefetched before the epilogue. cb = bid&7
// pins each strip group to one XCD's L2 (~512 KB hot).
// ---------------------------------------------------------------------------
__global__ __launch_bounds__(256, 2)
void ntxent_main(const unsigned short* __restrict__ zk,
                 const int* __restrict__ labels,
                 float* __restrict__ se_sum,
                 float* __restrict__ ps_sum) {
    __shared__ float rse[WROWS], rps[WROWS];
    const int tid  = threadIdx.x;
    const int wave = tid >> 6, lane = tid & 63;
    const int lrow = lane & 15, kgrp = lane >> 4;
    const int cb = blockIdx.x & 7, rb = blockIdx.x >> 3;   // XCD = bid%8 = cb
    const int rowW = rb * WROWS;
    const int strip = cb * 4 + wave;
    const int colStart = strip * CPW;

    if (tid < WROWS) { rse[tid] = 0.f; rps[tid] = 0.f; }

    // --- A fragments: 4 row-tiles x 8 k-chunks, contiguous 16B/lane ---
    short8 a[4][8];
    #pragma unroll
    for (int q = 0; q < 4; ++q) {
        const unsigned short* base = zk + (size_t)(rb * 4 + q) * 4096 + lane * 8;
        #pragma unroll
        for (int kk = 0; kk < 8; ++kk) a[q][kk] = *(const short8*)(base + kk * 512);
    }
    int labr[16];
    #pragma unroll
    for (int q = 0; q < 4; ++q)
        #pragma unroll
        for (int j = 0; j < 4; ++j)
            labr[q * 4 + j] = labels[rowW + q * 16 + kgrp * 4 + j];

    float se[16], ps[16];
    #pragma unroll
    for (int i = 0; i < 16; ++i) { se[i] = 0.f; ps[i] = 0.f; }

    const unsigned short* bbase = zk + (size_t)(strip * 16) * 4096 + lane * 8;
    short8 b[8];
    #pragma unroll
    for (int kk = 0; kk < 8; ++kk) b[kk] = *(const short8*)(bbase + kk * 512);

    #pragma unroll 1
    for (int t = 0; t < NT; ++t) {
        f32x4 c[4];
        #pragma unroll
        for (int q = 0; q < 4; ++q) c[q] = (f32x4){0.f, 0.f, 0.f, 0.f};
        #pragma unroll
        for (int kk = 0; kk < 8; ++kk) {
            c[0] = __builtin_amdgcn_mfma_f32_16x16x32_bf16(a[0][kk], b[kk], c[0], 0, 0, 0);
            c[1] = __builtin_amdgcn_mfma_f32_16x16x32_bf16(a[1][kk], b[kk], c[1], 0, 0, 0);
            c[2] = __builtin_amdgcn_mfma_f32_16x16x32_bf16(a[2][kk], b[kk], c[2], 0, 0, 0);
            c[3] = __builtin_amdgcn_mfma_f32_16x16x32_bf16(a[3][kk], b[kk], c[3], 0, 0, 0);
        }
        // prefetch next B tile (WAR on b: scheduled after last MFMA use,
        // L2 latency hides under the exp/ps epilogue below)
        if (t + 1 < NT) {
            const unsigned short* nb = bbase + (size_t)(t + 1) * 4096;
            #pragma unroll
            for (int kk = 0; kk < 8; ++kk) b[kk] = *(const short8*)(nb + kk * 512);
        }
        const int colBase = colStart + t * 16;
        const int gcol = colBase + lrow;
        const int labc = labels[gcol];
        float e[16];
        #pragma unroll
        for (int q = 0; q < 4; ++q)
            #pragma unroll
            for (int j = 0; j < 4; ++j) e[q * 4 + j] = exp2f(c[q][j]);
        if ((colBase < rowW + WROWS) && (rowW < colBase + 16)) {  // diag tile
            #pragma unroll
            for (int q = 0; q < 4; ++q)
                #pragma unroll
                for (int j = 0; j < 4; ++j)
                    if (gcol == rowW + q * 16 + kgrp * 4 + j) e[q * 4 + j] = 0.f;
        }
        #pragma unroll
        for (int q = 0; q < 4; ++q)
            #pragma unroll
            for (int j = 0; j < 4; ++j) {
                const int i = q * 4 + j;
                se[i] += e[i];
                ps[i] += (labc == labr[i]) ? c[q][j] : 0.f;  // incl self; fixed in final
            }
    }

    // --- reduce over the 16 col-lanes of each kgrp group ---
    #pragma unroll
    for (int i = 0; i < 16; ++i) {
        #pragma unroll
        for (int m = 1; m < 16; m <<= 1) {
            se[i] += __shfl_xor(se[i], m, 64);
            ps[i] += __shfl_xor(ps[i], m, 64);
        }
    }
    __syncthreads();                 // rse/rps init done
    if (lrow == 0) {
        #pragma unroll
        for (int i = 0; i < 16; ++i) {
            const int rl = (i >> 2) * 16 + kgrp * 4 + (i & 3);
            atomicAdd(&rse[rl], se[i]);
            atomicAdd(&rps[rl], ps[i]);
        }
    }
    __syncthreads();
    if (tid < WROWS) {
        atomicAdd(&se_sum[rowW + tid], rse[tid]);
        atomicAdd(&ps_sum[rowW + tid], rps[tid]);
    }
}

// ---------------------------------------------------------------------------
// Kernel 3: single-block finalize. LDS label histogram, per-row loss, scalar.
// ps included self (scaled ~SELFV): subtract SELFV; n_pos = hist[lab]-1.
// ---------------------------------------------------------------------------
__global__ __launch_bounds__(1024)
void ntxent_final(const float* __restrict__ se_sum,
                  const float* __restrict__ ps_sum,
                  const int* __restrict__ labels,
                  float* __restrict__ out) {
    __shared__ int hist[128];
    __shared__ float redc[16], redh[16];
    const int tid = threadIdx.x;
    if (tid < 128) hist[tid] = 0;
    __syncthreads();
    for (int i = tid; i < NROWS; i += 1024) atomicAdd(&hist[labels[i]], 1);
    __syncthreads();

    float contrib = 0.f, hp = 0.f;
    for (int i = tid; i < NROWS; i += 1024) {
        const int n = hist[labels[i]] - 1;
        if (n > 0) {
            const float lse  = __logf(se_sum[i]);
            const float mean = LN2 * (ps_sum[i] - SELFV) / (float)n;
            contrib += lse - mean;
            hp += 1.0f;
        }
    }
    #pragma unroll
    for (int m = 32; m; m >>= 1) {
        contrib += __shfl_xor(contrib, m, 64);
        hp      += __shfl_xor(hp, m, 64);
    }
    if ((tid & 63) == 0) { redc[tid >> 6] = contrib; redh[tid >> 6] = hp; }
    __syncthreads();
    if (tid == 0) {
        float c = 0.f, h = 0.f;
        #pragma unroll
        for (int w = 0; w < 16; ++w) { c += redc[w]; h += redh[w]; }
        out[0] = c / fmaxf(h, 1.0f);
    }
}

extern "C" void kernel_launch(void* const* d_in, const int* in_sizes, int n_in,
                              void* d_out, int out_size, void* d_ws, size_t ws_size,
                              hipStream_t stream) {
    const float* latent = (const float*)d_in[0];
    const int*   labels = (const int*)d_in[1];
    float* out = (float*)d_out;

    unsigned short* zk = (unsigned short*)d_ws;                       // 4 MB
    char* p = (char*)d_ws + (size_t)NROWS * DIM * sizeof(unsigned short);
    float* se_sum = (float*)p;                                        // 32 KB
    float* ps_sum = se_sum + NROWS;                                   // 32 KB

    hipMemsetAsync(p, 0, 2 * NROWS * sizeof(float), stream);
    normalize_kernel<<<NROWS / 4, 256, 0, stream>>>(latent, zk);
    ntxent_main<<<(NROWS / WROWS) * (STRIPS / 4), 256, 0, stream>>>(zk, labels, se_sum, ps_sum);
    ntxent_final<<<1, 1024, 0, stream>>>(se_sum, ps_sum, labels, out);
}